// Round 7
// baseline (765.989 us; speedup 1.0000x reference)
//
#include <hip/hip_runtime.h>
#include <hip/hip_bf16.h>

typedef __attribute__((ext_vector_type(8))) short short8;
typedef __attribute__((ext_vector_type(4))) float f32x4;
typedef __attribute__((ext_vector_type(16))) float f32x16;

#define CH 128
#define H 256
#define W 512
#define PH 258
#define PW 516
#define NTAPS 13
#define P_BYTES (PH * PW * CH * 2)   // 34,080,768
#define CHW (CH * H * W)

// per-chunk LDS buffer: 4 rows x 136 px-slots x 4 granules(16B) = 2176 + pad -> 2304
#define GRAN_PER_ROW 544             // 136 * 4
#define BUF_GRAN 2304                // 36 wave-loads x 64
#define BUF_SHORTS (BUF_GRAN * 8)    // 18432 shorts = 36,864 B
#define ROW_SHORTS (136 * 32)        // 4352 shorts per LDS row

#define GLD_LDS16(g, l)                                                        \
  __builtin_amdgcn_global_load_lds(                                            \
      (const __attribute__((address_space(1))) void*)(g),                      \
      (__attribute__((address_space(3))) void*)(l), 16, 0, 0)

// ---- kernel 1: premask + cast weights into 32x32x16 MFMA fragment order ----
// frag = t*32 + mib*8 + kk*2 + ks  (mib: 32-oc block, kk: 32-ic chunk, ks: 16-ic step)
// element (lane l, e): oc = mib*32 + (l&31), ic = kk*32 + ks*16 + (l>>5)*8 + e
__global__ void premask_weights(const float* __restrict__ w,
                                __hip_bfloat16* __restrict__ Wt3) {
    int idx  = blockIdx.x * 256 + threadIdx.x;   // 13*32*512 = 212992
    int frag = idx >> 9;
    int r    = idx & 511;
    int l    = r >> 3;
    int e    = r & 7;
    int t    = frag >> 5;
    int mib  = (frag >> 3) & 3;
    int kk   = (frag >> 1) & 3;
    int ks   = frag & 1;
    int oc   = mib * 32 + (l & 31);
    int ic   = kk * 32 + ks * 16 + (l >> 5) * 8 + e;
    int ky   = t < 5 ? 0 : (t < 10 ? 1 : 2);
    int kx   = t - ky * 5;
    float v  = w[(oc * CH + ic) * 25 + ky * 5 + kx];
    if (t == 12 && ((ic >> 4) > (oc >> 4))) v = 0.f;   // group-causal center tap
    Wt3[idx] = __float2bfloat16(v);
}

// ---- kernel 2: NCHW fp32 -> padded NHWC bf16 (one n) -----------------------
__global__ void transpose_pad_kernel(const float* __restrict__ xn,
                                     __hip_bfloat16* __restrict__ P) {
    __shared__ float tile[32][33];
    int h  = blockIdx.y;
    int wt = blockIdx.x & 15;
    int ct = blockIdx.x >> 4;
    int tx = threadIdx.x & 31;
    int ty = threadIdx.x >> 5;
#pragma unroll
    for (int r = 0; r < 4; ++r) {
        int c = ct * 32 + ty + r * 8;
        tile[ty + r * 8][tx] = xn[(c * H + h) * W + wt * 32 + tx];
    }
    __syncthreads();
    int wl = threadIdx.x >> 3;
    int cq = threadIdx.x & 7;
    union { ushort4 u; __hip_bfloat16 hh[4]; } v;
    v.hh[0] = __float2bfloat16(tile[cq * 4 + 0][wl]);
    v.hh[1] = __float2bfloat16(tile[cq * 4 + 1][wl]);
    v.hh[2] = __float2bfloat16(tile[cq * 4 + 2][wl]);
    v.hh[3] = __float2bfloat16(tile[cq * 4 + 3][wl]);
    *reinterpret_cast<ushort4*>(
        (unsigned short*)P +
        ((size_t)(h + 2) * PW + (wt * 32 + wl + 2)) * CH + ct * 32 + cq * 4) = v.u;
}

// ---- kernel 3: MFMA conv (32x32x16) + fused transpose tail for n+1 ---------
// Block: 128 oc x 2h x 128 w. 4 waves: wv>>1 = oc half (64), wv&1 = output row.
// Per-chunk LDS tile: [4 rows][136 px][32 ch] bf16, granule swizzle chk^=(px&3).
__global__ __launch_bounds__(256, 2)
void conv_mfma(const __hip_bfloat16* __restrict__ P,
               const __hip_bfloat16* __restrict__ Wt3,
               const float* __restrict__ bias,
               const float* __restrict__ slope,
               float* __restrict__ outn,
               const float* __restrict__ xnext,     // null if none
               __hip_bfloat16* __restrict__ Pnext) {
    __shared__ short lds[2 * BUF_SHORTS];   // 73,728 B -> 2 blocks/CU
    int h0    = blockIdx.y << 1;
    int w0    = blockIdx.x << 7;
    int tid   = threadIdx.x;
    int lane  = tid & 63;
    int wv    = tid >> 6;
    int l31   = lane & 31;
    int lhi   = lane >> 5;            // 0..1
    int obf2  = wv >> 1;              // oc half
    int hsel  = wv & 1;               // output row within pair

    f32x16 acc[2][4];
#pragma unroll
    for (int mi = 0; mi < 2; ++mi)
#pragma unroll
        for (int ni = 0; ni < 4; ++ni)
            acc[mi][ni] = (f32x16){0.f};

    const short* Wt3s = (const short*)Wt3;

    // ---- precompute stage source offsets (shorts from P) once --------------
    int stoff[9];
#pragma unroll
    for (int i = 0; i < 9; ++i) {
        int s    = wv + i * 4;
        int g64  = (s << 6) + lane;
        int row  = (g64 >= 544) + (g64 >= 1088) + (g64 >= 1632) + (g64 >= 2176);
        int rem  = g64 - row * GRAN_PER_ROW;
        int px   = rem >> 2;
        int chk  = rem & 3;
        int rowc = row < 4 ? row : 3;
        int pxc  = px < 132 ? px : 131;
        int ccs  = chk ^ (px & 3);
        stoff[i] = ((h0 + rowc) * PW + (w0 + pxc)) * CH + ccs * 8;
    }
    // per-lane B offsets (shorts) for each kx and kstep, within a row
    int bqk[5][2];
#pragma unroll
    for (int kx = 0; kx < 5; ++kx) {
        int pxb = kx + l31;
#pragma unroll
        for (int ks = 0; ks < 2; ++ks)
            bqk[kx][ks] = (pxb * 4 + ((ks * 2 + lhi) ^ (pxb & 3))) * 8;
    }

    auto stage = [&](int kk, int b) {
#pragma unroll
        for (int i = 0; i < 9; ++i)
            GLD_LDS16(P + stoff[i] + kk * 32,
                      (char*)lds + b * (BUF_SHORTS * 2) + ((wv + i * 4) << 10));
    };

    stage(0, 0);
    __syncthreads();

    for (int kk = 0; kk < 4; ++kk) {
        int cur = kk & 1;
        if (kk < 3) stage(kk + 1, cur ^ 1);     // prefetch next chunk

        // A base: t*16384 + (obf2*2+mi)*4096 + kk*1024 + ks*512 + lane*8
        const short* apb = Wt3s + obf2 * 8192 + kk * 1024 + (lane << 3);
        const short* bb  = lds + cur * BUF_SHORTS;
#pragma unroll
        for (int t = 0; t < NTAPS; ++t) {
            int ky  = t < 5 ? 0 : (t < 10 ? 1 : 2);
            int kx  = t - ky * 5;
            const short* ap = apb + t * 16384;
            const short* bp = bb + (hsel + ky) * ROW_SHORTS;
            short8 a[2][2], b[4][2];
#pragma unroll
            for (int mi = 0; mi < 2; ++mi)
#pragma unroll
                for (int ks = 0; ks < 2; ++ks)
                    a[mi][ks] = *reinterpret_cast<const short8*>(
                        ap + mi * 4096 + ks * 512);
#pragma unroll
            for (int ni = 0; ni < 4; ++ni)
#pragma unroll
                for (int ks = 0; ks < 2; ++ks)
                    b[ni][ks] = *reinterpret_cast<const short8*>(
                        bp + bqk[kx][ks] + ni * 1024);
            __builtin_amdgcn_s_setprio(1);
#pragma unroll
            for (int mi = 0; mi < 2; ++mi)
#pragma unroll
                for (int ni = 0; ni < 4; ++ni)
#pragma unroll
                    for (int ks = 0; ks < 2; ++ks)
                        acc[mi][ni] = __builtin_amdgcn_mfma_f32_32x32x16_bf16(
                            a[mi][ks], b[ni][ks], acc[mi][ni], 0, 0, 0);
            __builtin_amdgcn_s_setprio(0);
        }
        __syncthreads();
    }

    // ---- epilogue: bias + per-channel leaky relu ----------------------------
    // C/D: col(px) = lane&31, row(oc) = (r&3) + 8*(r>>2) + 4*(lane>>5)
    int hrow = h0 + hsel;
#pragma unroll
    for (int mi = 0; mi < 2; ++mi) {
#pragma unroll
        for (int q = 0; q < 4; ++q) {
            int oc0 = obf2 * 64 + mi * 32 + q * 8 + 4 * lhi;
            f32x4 b4 = *reinterpret_cast<const f32x4*>(bias + oc0);
            f32x4 s4 = *reinterpret_cast<const f32x4*>(slope + oc0);
#pragma unroll
            for (int j = 0; j < 4; ++j) {
                float* orow = outn + ((oc0 + j) * H + hrow) * W + w0;
#pragma unroll
                for (int ni = 0; ni < 4; ++ni) {
                    float v = acc[mi][ni][q * 4 + j] + b4[j];
                    v = v > 0.f ? v : s4[j] * v;
                    orow[ni * 32 + l31] = v;
                }
            }
        }
    }

    // ---- fused transpose tail: NCHW fp32 x[n+1] -> Pnext (32 tiles/block) --
    if (xnext) {
        float* sc = (float*)lds;             // 32x33 scratch
        int cb = blockIdx.y * 4 + blockIdx.x;   // 0..511
        int tx = tid & 31;
        int ty = tid >> 5;
        int wl = tid >> 3;
        int cq = tid & 7;
        for (int i = 0; i < 32; ++i) {
            int vt  = cb * 32 + i;
            int hh  = vt >> 6;
            int vbx = vt & 63;
            int wt  = vbx & 15;
            int ct  = vbx >> 4;
            __syncthreads();
#pragma unroll
            for (int r = 0; r < 4; ++r) {
                int c = ct * 32 + ty + r * 8;
                sc[(ty + r * 8) * 33 + tx] = xnext[(c * H + hh) * W + wt * 32 + tx];
            }
            __syncthreads();
            union { ushort4 u; __hip_bfloat16 hh4[4]; } v;
            v.hh4[0] = __float2bfloat16(sc[(cq * 4 + 0) * 33 + wl]);
            v.hh4[1] = __float2bfloat16(sc[(cq * 4 + 1) * 33 + wl]);
            v.hh4[2] = __float2bfloat16(sc[(cq * 4 + 2) * 33 + wl]);
            v.hh4[3] = __float2bfloat16(sc[(cq * 4 + 3) * 33 + wl]);
            *reinterpret_cast<ushort4*>(
                (unsigned short*)Pnext +
                ((size_t)(hh + 2) * PW + (wt * 32 + wl + 2)) * CH + ct * 32 + cq * 4) = v.u;
        }
    }
}

extern "C" void kernel_launch(void* const* d_in, const int* in_sizes, int n_in,
                              void* d_out, int out_size, void* d_ws, size_t ws_size,
                              hipStream_t stream) {
    const float* x      = (const float*)d_in[0];
    const float* weight = (const float*)d_in[1];
    const float* bias   = (const float*)d_in[2];
    const float* slope  = (const float*)d_in[3];
    float* out = (float*)d_out;

    __hip_bfloat16* P0  = (__hip_bfloat16*)d_ws;
    __hip_bfloat16* P1  = (__hip_bfloat16*)((char*)d_ws + P_BYTES);
    __hip_bfloat16* Wt3 = (__hip_bfloat16*)((char*)d_ws + 2 * (size_t)P_BYTES);
    __hip_bfloat16* Pp[2] = {P0, P1};

    (void)hipMemsetAsync(d_ws, 0, 2 * (size_t)P_BYTES, stream);  // zero pads once
    premask_weights<<<832, 256, 0, stream>>>(weight, Wt3);
    transpose_pad_kernel<<<dim3(64, 256), 256, 0, stream>>>(x, P0);

    for (int n = 0; n < 8; ++n) {
        const float* xnext = (n < 7) ? x + (size_t)(n + 1) * CHW : nullptr;
        conv_mfma<<<dim3(4, 128), 256, 0, stream>>>(
            Pp[n & 1], Wt3, bias, slope, out + (size_t)n * CHW,
            xnext, Pp[(n + 1) & 1]);
    }
}

// Round 8
// 592.039 us; speedup vs baseline: 1.2938x; 1.2938x over previous
//
#include <hip/hip_runtime.h>
#include <hip/hip_bf16.h>

typedef __attribute__((ext_vector_type(8))) short short8;
typedef __attribute__((ext_vector_type(4))) float f32x4;

#define CH 128
#define H 256
#define W 512
#define PH 258
#define PW 516
#define NTAPS 13
#define P_BYTES (PH * PW * CH * 2)       // 34,080,768 per slab
#define P_SHORTS (PH * PW * CH)
#define CHW (CH * H * W)

// per-chunk LDS buffer: 6 rows x 136 px x 4 granules(16B) = 3264 -> pad 3328 (52 loads)
#define GRAN_PER_ROW 544                 // 136 * 4
#define NLOADS 52
#define BUF_SHORTS (3328 * 8)            // 26624 shorts = 53,248 B
#define ROW_SHORTS (136 * 32)            // 4352 shorts per LDS row

#define GLD_LDS16(g, l)                                                        \
  __builtin_amdgcn_global_load_lds(                                            \
      (const __attribute__((address_space(1))) void*)(g),                      \
      (__attribute__((address_space(3))) void*)(l), 16, 0, 0)

// ---- kernel 0: zero the pad borders of all 8 P slabs (per call) ------------
__global__ void zero_pads(unsigned int* __restrict__ Pd) {
    int row  = blockIdx.x;               // 0..257
    int slab = blockIdx.y;               // 0..7
    unsigned int* base = Pd + (size_t)slab * (P_SHORTS / 2);
    int tid = threadIdx.x;
    if (row < 2) {                       // full top rows
        unsigned int* r = base + (size_t)row * (PW * 64);
        for (int i = tid; i < PW * 64; i += 256) r[i] = 0u;
    } else {                             // side cols {0,1,514,515}
        int seg = tid >> 6;
        int col = seg < 2 ? seg : 512 + seg;
        base[((size_t)row * PW + col) * 64 + (tid & 63)] = 0u;
    }
}

// ---- kernel 1: premask + cast weights into 16x16 MFMA-fragment order -------
// Wt2 element idx = fragIdx*512 + lane*8 + e, fragIdx = (t*8 + ob)*4 + kcg
// lane: oc = ob*16 + (lane&15), ic = kcg*32 + (lane>>4)*8 + e
__global__ void premask_weights(const float* __restrict__ w,
                                __hip_bfloat16* __restrict__ Wt2) {
    int idx  = blockIdx.x * 256 + threadIdx.x;   // 13*8*4*512 = 212992
    int frag = idx >> 9;
    int r    = idx & 511;
    int l    = r >> 3;
    int e    = r & 7;
    int t    = frag >> 5;
    int ob   = (frag >> 2) & 7;
    int kcg  = frag & 3;
    int oc   = ob * 16 + (l & 15);
    int ic   = kcg * 32 + (l >> 4) * 8 + e;
    int ky   = t < 5 ? 0 : (t < 10 ? 1 : 2);
    int kx   = t - ky * 5;
    float v  = w[(oc * CH + ic) * 25 + ky * 5 + kx];
    if (t == 12 && ((ic >> 4) > (oc >> 4))) v = 0.f;   // group-causal center tap
    Wt2[idx] = __float2bfloat16(v);
}

// ---- kernel 2: NCHW fp32 -> padded NHWC bf16, all 8 n ----------------------
__global__ void transpose_pad_all(const float* __restrict__ x,
                                  __hip_bfloat16* __restrict__ Pbase) {
    __shared__ float tile[32][33];
    const float* xn = x + (size_t)blockIdx.z * CHW;
    unsigned short* P = (unsigned short*)(Pbase + (size_t)blockIdx.z * P_SHORTS);
    int h  = blockIdx.y;
    int wt = blockIdx.x & 15;
    int ct = blockIdx.x >> 4;
    int tx = threadIdx.x & 31;
    int ty = threadIdx.x >> 5;
#pragma unroll
    for (int r = 0; r < 4; ++r) {
        int c = ct * 32 + ty + r * 8;
        tile[ty + r * 8][tx] = xn[(c * H + h) * W + wt * 32 + tx];
    }
    __syncthreads();
    int wl = threadIdx.x >> 3;
    int cq = threadIdx.x & 7;
    union { ushort4 u; __hip_bfloat16 hh[4]; } v;
    v.hh[0] = __float2bfloat16(tile[cq * 4 + 0][wl]);
    v.hh[1] = __float2bfloat16(tile[cq * 4 + 1][wl]);
    v.hh[2] = __float2bfloat16(tile[cq * 4 + 2][wl]);
    v.hh[3] = __float2bfloat16(tile[cq * 4 + 3][wl]);
    *reinterpret_cast<ushort4*>(
        P + ((size_t)(h + 2) * PW + (wt * 32 + wl + 2)) * CH + ct * 32 + cq * 4) = v.u;
}

// ---- kernel 3: MFMA conv, all n; 128 oc x 4h x 128 w per block -------------
// 8 waves: hsel = wv>>1 (output row 0..3), obf = (wv&1)*4 (oc half).
// Per-chunk LDS tile: [6 rows][136 px][32 ch] bf16, granule swizzle chk^=(px&3).
// Pipeline: stage(0) -> [issue stage(kk+1); compute(kk); barrier] x4.
__global__ __launch_bounds__(512, 2)
void conv_mfma_all(const __hip_bfloat16* __restrict__ Pbase,
                   const __hip_bfloat16* __restrict__ Wt2,
                   const float* __restrict__ bias,
                   const float* __restrict__ slope,
                   float* __restrict__ out) {
    __shared__ short lds[2 * BUF_SHORTS];   // 106,496 B -> 1 block/CU
    const __hip_bfloat16* P = Pbase + (size_t)blockIdx.z * P_SHORTS;
    float* outn = out + (size_t)blockIdx.z * CHW;
    int h0    = blockIdx.y << 2;
    int w0    = blockIdx.x << 7;
    int tid   = threadIdx.x;
    int lane  = tid & 63;
    int wv    = tid >> 6;                // 0..7
    int l15   = lane & 15;
    int khi   = lane >> 4;               // 0..3
    int obf   = (wv & 1) * 4;            // oc fragment base (0 or 4)
    int hsel  = wv >> 1;                 // output row 0..3

    f32x4 acc[4][8];
#pragma unroll
    for (int mi = 0; mi < 4; ++mi)
#pragma unroll
        for (int ni = 0; ni < 8; ++ni)
            acc[mi][ni] = (f32x4){0.f, 0.f, 0.f, 0.f};

    const short* Wt2s = (const short*)Wt2;

    // ---- precompute stage source offsets (shorts from P) once --------------
    int stoff[7];
#pragma unroll
    for (int i = 0; i < 7; ++i) {
        int s    = wv + i * 8;           // 0..55; only s<52 used
        int g64  = (s << 6) + lane;      // granule 0..3583
        int row  = (g64 >= 544) + (g64 >= 1088) + (g64 >= 1632) +
                   (g64 >= 2176) + (g64 >= 2720);
        int rem  = g64 - row * GRAN_PER_ROW;
        int px   = rem >> 2;
        int chk  = rem & 3;
        int pxc  = px < 132 ? px : 131;  // clamp unused slots
        int ccs  = chk ^ (pxc & 3);      // inverse-swizzled source
        stoff[i] = ((h0 + row) * PW + (w0 + pxc)) * CH + ccs * 8;
    }
    // per-lane B offsets (shorts) for each kx, within a row
    int bq[5];
#pragma unroll
    for (int kx = 0; kx < 5; ++kx) {
        int pxb = kx + l15;
        bq[kx] = (pxb * 4 + (khi ^ (pxb & 3))) * 8;
    }

    auto stage = [&](int kk, int b) {
#pragma unroll
        for (int i = 0; i < 7; ++i) {
            int s = wv + i * 8;
            if (s < NLOADS)
                GLD_LDS16(P + stoff[i] + kk * 32,
                          (char*)lds + b * (BUF_SHORTS * 2) + (s << 10));
        }
    };

    stage(0, 0);
    __syncthreads();

    for (int kk = 0; kk < 4; ++kk) {
        int cur = kk & 1;
        if (kk < 3) stage(kk + 1, cur ^ 1);     // prefetch next chunk

        const short* apb = Wt2s + ((obf * 4 + kk) << 9) + (lane << 3);
        const short* bb  = lds + cur * BUF_SHORTS + hsel * ROW_SHORTS;
#pragma unroll
        for (int t = 0; t < NTAPS; ++t) {
            int ky  = t < 5 ? 0 : (t < 10 ? 1 : 2);
            int kx  = t - ky * 5;
            const short* ap = apb + t * 16384;
            const short* bp = bb + ky * ROW_SHORTS + bq[kx];
            short8 a[4], b[8];
#pragma unroll
            for (int mi = 0; mi < 4; ++mi)
                a[mi] = *reinterpret_cast<const short8*>(ap + mi * 2048);
#pragma unroll
            for (int ni = 0; ni < 8; ++ni)
                b[ni] = *reinterpret_cast<const short8*>(bp + ni * 512);
            __builtin_amdgcn_s_setprio(1);
#pragma unroll
            for (int mi = 0; mi < 4; ++mi)
#pragma unroll
                for (int ni = 0; ni < 8; ++ni)
                    acc[mi][ni] = __builtin_amdgcn_mfma_f32_16x16x32_bf16(
                        a[mi], b[ni], acc[mi][ni], 0, 0, 0);
            __builtin_amdgcn_s_setprio(0);
        }
        __syncthreads();   // drains prefetch + protects buf reuse
    }

    // ---- epilogue: bias + per-channel leaky relu ----------------------------
    int hrow = h0 + hsel;
#pragma unroll
    for (int mi = 0; mi < 4; ++mi) {
        int ocb = obf * 16 + mi * 16 + 4 * khi;
        f32x4 b4 = *reinterpret_cast<const f32x4*>(bias + ocb);
        f32x4 s4 = *reinterpret_cast<const f32x4*>(slope + ocb);
#pragma unroll
        for (int i = 0; i < 4; ++i) {
            float* orow = outn + ((ocb + i) * H + hrow) * W + w0;
#pragma unroll
            for (int ni = 0; ni < 8; ++ni) {
                float v = acc[mi][ni][i] + b4[i];
                v = v > 0.f ? v : s4[i] * v;
                orow[ni * 16 + l15] = v;
            }
        }
    }
}

extern "C" void kernel_launch(void* const* d_in, const int* in_sizes, int n_in,
                              void* d_out, int out_size, void* d_ws, size_t ws_size,
                              hipStream_t stream) {
    const float* x      = (const float*)d_in[0];
    const float* weight = (const float*)d_in[1];
    const float* bias   = (const float*)d_in[2];
    const float* slope  = (const float*)d_in[3];
    float* out = (float*)d_out;

    __hip_bfloat16* Pbase = (__hip_bfloat16*)d_ws;                 // 8 slabs
    __hip_bfloat16* Wt2   = (__hip_bfloat16*)((char*)d_ws + 8 * (size_t)P_BYTES);

    zero_pads<<<dim3(PH, 8), 256, 0, stream>>>((unsigned int*)d_ws);
    premask_weights<<<832, 256, 0, stream>>>(weight, Wt2);
    transpose_pad_all<<<dim3(64, 256, 8), 256, 0, stream>>>(x, Pbase);
    conv_mfma_all<<<dim3(4, 64, 8), 512, 0, stream>>>(Pbase, Wt2, bias, slope, out);
}